// Round 7
// baseline (132.085 us; speedup 1.0000x reference)
//
#include <hip/hip_runtime.h>

// CTC batch cost (Keras semantics): blank = C-1, full-length inputs/labels.
// Two-phase:
//   Phase 1 (ctc_gather4): per (b,t,lane) emit float4 {p[l0]+EPS, p[l1]+EPS,
//     p[blank]+EPS, 0} -> cmp[B][T][64]. Coalesced 16B stores.
//   Phase 2 (ctc_scan_lds): scaled linear-domain forward DP, one wave/row.
//     R6 lesson: a VMEM register ring never gets 32 loads in flight (compiler
//     won't emit counted vmcnt pipelines from source). Fix: double-buffered
//     LDS staging via global_load_lds (no dest VGPR -> can't be sunk), one
//     s_waitcnt vmcnt(0) per 32-step chunk, issued BEFORE the chunk compute
//     so ~900cy latency hides under ~1300cy of compute. LDS->reg via an
//     8-deep ds_read_b128 ring (compiler's counted lgkmcnt is good).
//     DPP wave_shr:1 cross-lane shift; per-lane pow2 rescale every 4 steps.

constexpr int   B_DIM = 64;
constexpr int   T_LEN = 1024;
constexpr int   C_DIM = 512;
constexpr int   L_LEN = 128;
constexpr int   BLANK = C_DIM - 1;
constexpr int   TC    = 32;            // timesteps per staged chunk
constexpr int   NCH   = T_LEN / TC;    // 32 chunks
constexpr float EPSF  = 1e-7f;
constexpr float LN2F  = 0.69314718055994530942f;

// lane l <- lane l-1, lane 0 <- 0 (DPP wave_shr:1, bound_ctrl=0-fill). VALU-only.
__device__ __forceinline__ float wshr1_f(float x) {
    return __int_as_float(__builtin_amdgcn_update_dpp(
        0, __float_as_int(x), 0x138, 0xf, 0xf, true));
}
__device__ __forceinline__ int wshr1_i(int x) {
    return __builtin_amdgcn_update_dpp(0, x, 0x138, 0xf, 0xf, true);
}

__global__ __launch_bounds__(256)
void ctc_gather4(const int* __restrict__ yt, const float* __restrict__ yh,
                 float4* __restrict__ cmp)
{
    const int id = blockIdx.x * 256 + threadIdx.x;   // over B*T*64
    constexpr int NTOT = B_DIM * T_LEN * 64;
    if (id >= NTOT) return;
    const int lane = id & 63;
    const int bt   = id >> 6;
    const int b    = bt >> 10;                       // T_LEN = 1024
    const int* __restrict__ lb = yt + b * L_LEN;
    const float* __restrict__ row = yh + (size_t)bt * C_DIM;
    float4 v;
    v.x = row[lb[2 * lane]]     + EPSF;              // state 4l+1
    v.y = row[lb[2 * lane + 1]] + EPSF;              // state 4l+3
    v.z = row[BLANK]            + EPSF;              // blank (per-lane copy)
    v.w = 0.0f;
    cmp[id] = v;                                     // coalesced 16B store
}

__global__ __launch_bounds__(64, 1)
void ctc_scan_lds(const int* __restrict__ yt, const float4* __restrict__ cmp,
                  float* __restrict__ out)
{
    __shared__ float4 sbuf[2][TC][64];               // 2 x 32KB

    const int b    = blockIdx.x;
    const int lane = threadIdx.x;
    const int* __restrict__ lb = yt + b * L_LEN;

    const int l0 = lb[2 * lane];                    // state 4l+1
    const int l1 = lb[2 * lane + 1];                // state 4l+3
    const int lp = lane ? lb[2 * lane - 1] : 0;
    const float sk1 = (lane > 0 && l0 != lp && l0 != BLANK) ? 1.0f : 0.0f;
    const float sk3 = (l1 != l0 && l1 != BLANK) ? 1.0f : 0.0f;

    const float4* __restrict__ base = cmp + (size_t)b * T_LEN * 64;  // [t][lane]

    auto stage = [&](int buf, int chunk) {          // 32 async 16B loads
        const float4* g = base + (size_t)chunk * TC * 64 + lane;
#pragma unroll
        for (int i = 0; i < TC; ++i) {
            __builtin_amdgcn_global_load_lds(
                (const __attribute__((address_space(1))) void*)(g + i * 64),
                (__attribute__((address_space(3))) void*)&sbuf[buf][i][0],
                16, 0, 0);
        }
    };

    // "t=-1" init: a0=1 on lane 0 makes step t=0 produce exactly alpha0.
    float a0 = (lane == 0) ? 1.0f : 0.0f;
    float a1 = 0.0f, a2 = 0.0f, a3 = 0.0f, a4 = 0.0f;
    int   E  = 0;                                   // per-lane exponent
    float sSeed = (lane == 0) ? 0.0f : 1.0f;        // 2^(E_prev - E), 0 masks lane 0

    stage(0, 0);
    asm volatile("s_waitcnt vmcnt(0)" ::: "memory");

    float4 ring[8];
#pragma unroll 1
    for (int c = 0; c < NCH; ++c) {
        const int buf = c & 1;
        if (c + 1 < NCH) stage(buf ^ 1, c + 1);     // prefetch next chunk -> other buf

#pragma unroll
        for (int i = 0; i < 8; ++i) ring[i] = sbuf[buf][i][lane];

#pragma unroll 1
        for (int tq = 0; tq < TC / 8; ++tq) {
#pragma unroll
            for (int i = 0; i < 8; ++i) {
                const float P1 = ring[i].x;
                const float P3 = ring[i].y;
                const float Pb = ring[i].z;
                if (tq < TC / 8 - 1)
                    ring[i] = sbuf[buf][tq * 8 + i + 8][lane];

                const float pa3 = wshr1_f(a3) * sSeed;    // alpha[4l-1], rescaled
                const float n0 = Pb * (a0 + pa3);
                const float n1 = P1 * (a1 + a0 + sk1 * pa3);
                const float n2 = Pb * (a2 + a1);
                const float n3 = P3 * (a3 + a2 + sk3 * a1);
                const float n4 = Pb * (a4 + a3);
                a0 = n0; a1 = n1; a2 = n2; a3 = n3; a4 = n4;

                if ((i & 3) == 3) {
                    // per-lane rescale every 4 steps (decay >= (1e-7)^4 = 2^-93)
                    const float m = fmaxf(fmaxf(fmaxf(a0, a1), fmaxf(a2, a3)), a4);
                    const bool has = m > 0.0f;
                    int eb = (int)((__float_as_uint(m) >> 23) & 0xFFu);
                    eb = eb < 1 ? 1 : eb;           // denormal m -> scale up
                    if (has) {
                        const float scl = __uint_as_float((unsigned)(254 - eb) << 23);
                        a0 *= scl; a1 *= scl; a2 *= scl; a3 *= scl; a4 *= scl;
                        E += eb - 127;
                    }
                    int pE = wshr1_i(E);
                    if (!has && lane > 0) E = pE;   // empty lane adopts neighbor's E
                    pE = wshr1_i(E);
                    const int d = pE - E;
                    sSeed = (lane == 0 || d < -126)
                          ? 0.0f
                          : __uint_as_float((unsigned)(127 + (d > 126 ? 126 : d)) << 23);
                }
            }
        }
        if (c + 1 < NCH)
            asm volatile("s_waitcnt vmcnt(0)" ::: "memory");  // next buf ready (free: hidden)
    }

    if (lane == 63)                                 // states 255 (a3) + 256 (a4)
        out[b] = -((log2f(a3 + a4) + (float)E) * LN2F);
}

// Fallback (no workspace): direct 3-gather scan on yh.
__global__ __launch_bounds__(64, 1)
void ctc_scan_direct(const int* __restrict__ yt, const float* __restrict__ src,
                     float* __restrict__ out)
{
    const int b    = blockIdx.x;
    const int lane = threadIdx.x;
    const int* __restrict__ lb = yt + b * L_LEN;

    const int l0 = lb[2 * lane];
    const int l1 = lb[2 * lane + 1];
    const int lp = lane ? lb[2 * lane - 1] : 0;
    const float sk1 = (lane > 0 && l0 != lp && l0 != BLANK) ? 1.0f : 0.0f;
    const float sk3 = (l1 != l0 && l1 != BLANK) ? 1.0f : 0.0f;

    const float* __restrict__ base = src + (size_t)b * T_LEN * C_DIM;

    float a0 = (lane == 0) ? 1.0f : 0.0f;
    float a1 = 0.0f, a2 = 0.0f, a3 = 0.0f, a4 = 0.0f;
    int   E  = 0;
    float sSeed = (lane == 0) ? 0.0f : 1.0f;

    constexpr int DEPTH = 16;
    float pb[DEPTH], p1[DEPTH], p3[DEPTH];
    auto LOADT = [&](int slot, int t) {
        const float* row = base + (size_t)t * C_DIM;
        pb[slot] = row[BLANK]; p1[slot] = row[l0]; p3[slot] = row[l1];
    };
#pragma unroll
    for (int i = 0; i < DEPTH; ++i) LOADT(i, i);

#pragma unroll 1
    for (int blk = 0; blk < T_LEN / DEPTH; ++blk) {
#pragma unroll
        for (int q = 0; q < DEPTH / 4; ++q) {
#pragma unroll
            for (int i = 0; i < 4; ++i) {
                const int slot = q * 4 + i;
                const float Pb = pb[slot] + EPSF;
                const float P1 = p1[slot] + EPSF;
                const float P3 = p3[slot] + EPSF;
                int tn = blk * DEPTH + slot + DEPTH;
                tn = tn < T_LEN ? tn : T_LEN - 1;
                LOADT(slot, tn);
                const float pa3 = wshr1_f(a3) * sSeed;
                const float n0 = Pb * (a0 + pa3);
                const float n1 = P1 * (a1 + a0 + sk1 * pa3);
                const float n2 = Pb * (a2 + a1);
                const float n3 = P3 * (a3 + a2 + sk3 * a1);
                const float n4 = Pb * (a4 + a3);
                a0 = n0; a1 = n1; a2 = n2; a3 = n3; a4 = n4;
            }
            const float m = fmaxf(fmaxf(fmaxf(a0, a1), fmaxf(a2, a3)), a4);
            const bool has = m > 0.0f;
            int eb = (int)((__float_as_uint(m) >> 23) & 0xFFu);
            eb = eb < 1 ? 1 : eb;
            if (has) {
                const float scl = __uint_as_float((unsigned)(254 - eb) << 23);
                a0 *= scl; a1 *= scl; a2 *= scl; a3 *= scl; a4 *= scl;
                E += eb - 127;
            }
            int pE = wshr1_i(E);
            if (!has && lane > 0) E = pE;
            pE = wshr1_i(E);
            const int d = pE - E;
            sSeed = (lane == 0 || d < -126)
                  ? 0.0f
                  : __uint_as_float((unsigned)(127 + (d > 126 ? 126 : d)) << 23);
        }
    }

    if (lane == 63)
        out[b] = -((log2f(a3 + a4) + (float)E) * LN2F);
}

extern "C" void kernel_launch(void* const* d_in, const int* in_sizes, int n_in,
                              void* d_out, int out_size, void* d_ws, size_t ws_size,
                              hipStream_t stream)
{
    const int*   yt  = (const int*)d_in[0];
    const float* yh  = (const float*)d_in[1];
    float*       out = (float*)d_out;

    const size_t need = (size_t)B_DIM * T_LEN * 64 * sizeof(float4);
    if (d_ws != nullptr && ws_size >= need) {
        float4* cmp = (float4*)d_ws;
        constexpr int NTOT = B_DIM * T_LEN * 64;
        ctc_gather4<<<dim3((NTOT + 255) / 256), dim3(256), 0, stream>>>(yt, yh, cmp);
        ctc_scan_lds<<<dim3(B_DIM), dim3(64), 0, stream>>>(yt, cmp, out);
    } else {
        ctc_scan_direct<<<dim3(B_DIM), dim3(64), 0, stream>>>(yt, yh, out);
    }
}

// Round 12
// 85.367 us; speedup vs baseline: 1.5473x; 1.5473x over previous
//
#include <hip/hip_runtime.h>

// CTC batch cost (Keras semantics): blank = C-1, full-length inputs/labels.
// Two-phase:
//   Phase 1 (ctc_gather4): per (b,t,lane) emit float4 {p[l0]+EPS, p[l1]+EPS,
//     p[blank]+EPS, 0} -> cmp[B][T][64]. Coalesced 16B stores.
//   Phase 2 (ctc_scan_pc): producer/consumer waves. R8-R11 showed manual
//     asm VMEM rings are unfixable (async reg writes break SSA; copies read
//     stale data). Instead: TLP. Wave 1 = producer: global_load_lds staging
//     (proven in R7) with counted vmcnt(32) + RAW s_barrier (no auto-drain,
//     m201/T3/T4 pattern). Wave 0 = consumer: ZERO VMEM in loop (so the
//     compiler inserts no vmcnt drains -- R7's failure), ds_read_b128 ring.
//     4 LDS buffers x 32 steps (128KB), 2 chunks in flight, 1 barrier/chunk.
//     DPP wave_shr:1 cross-lane shift; per-lane pow2 rescale every 4 steps
//     (unbounded dynamic range; absmax 0.0 whenever mechanics were right).

constexpr int   B_DIM = 64;
constexpr int   T_LEN = 1024;
constexpr int   C_DIM = 512;
constexpr int   L_LEN = 128;
constexpr int   BLANK = C_DIM - 1;
constexpr int   TC    = 32;            // timesteps per chunk
constexpr int   NCH   = T_LEN / TC;    // 32 chunks
constexpr int   NBUF  = 4;             // LDS buffers (128 KB)
constexpr float EPSF  = 1e-7f;
constexpr float LN2F  = 0.69314718055994530942f;

// lane l <- lane l-1, lane 0 <- 0 (DPP wave_shr:1, bound_ctrl=0-fill). VALU-only.
__device__ __forceinline__ float wshr1_f(float x) {
    return __int_as_float(__builtin_amdgcn_update_dpp(
        0, __float_as_int(x), 0x138, 0xf, 0xf, true));
}
__device__ __forceinline__ int wshr1_i(int x) {
    return __builtin_amdgcn_update_dpp(0, x, 0x138, 0xf, 0xf, true);
}

__global__ __launch_bounds__(256)
void ctc_gather4(const int* __restrict__ yt, const float* __restrict__ yh,
                 float4* __restrict__ cmp)
{
    const int id = blockIdx.x * 256 + threadIdx.x;   // over B*T*64
    constexpr int NTOT = B_DIM * T_LEN * 64;
    if (id >= NTOT) return;
    const int lane = id & 63;
    const int bt   = id >> 6;
    const int b    = bt >> 10;                       // T_LEN = 1024
    const int* __restrict__ lb = yt + b * L_LEN;
    const float* __restrict__ row = yh + (size_t)bt * C_DIM;
    float4 v;
    v.x = row[lb[2 * lane]]     + EPSF;              // state 4l+1
    v.y = row[lb[2 * lane + 1]] + EPSF;              // state 4l+3
    v.z = row[BLANK]            + EPSF;              // blank (per-lane copy)
    v.w = 0.0f;
    cmp[id] = v;                                     // coalesced 16B store
}

__global__ __launch_bounds__(128, 1)
void ctc_scan_pc(const int* __restrict__ yt, const float4* __restrict__ cmp,
                 float* __restrict__ out)
{
    __shared__ float4 sbuf[NBUF][TC][64];            // 128 KB

    const int b    = blockIdx.x;
    const int tid  = threadIdx.x;
    const int lane = tid & 63;
    const int wid  = tid >> 6;                       // 0 = consumer, 1 = producer

    const float4* __restrict__ base = cmp + (size_t)b * T_LEN * 64;  // [t][lane]

    if (wid == 1) {
        // ---------------- producer wave: staging only, no LDS reads --------
        auto stage = [&](int ch) {
            const float4* g = base + (size_t)ch * TC * 64 + lane;
            float4* dst = &sbuf[ch & (NBUF - 1)][0][0];
#pragma unroll
            for (int i = 0; i < TC; ++i) {
                __builtin_amdgcn_global_load_lds(
                    (const __attribute__((address_space(1))) void*)(g + i * 64),
                    (__attribute__((address_space(3))) void*)(dst + i * 64),
                    16, 0, 0);
            }
        };
        asm volatile("s_waitcnt vmcnt(0)" ::: "memory");  // clean count baseline
        stage(0);
        stage(1);
        asm volatile("s_waitcnt vmcnt(32)" ::: "memory"); // chunk 0 landed
        __builtin_amdgcn_sched_barrier(0);
        __builtin_amdgcn_s_barrier();                     // raw: no auto-drain
#pragma unroll 1
        for (int c = 0; c < NCH; ++c) {
            if (c < NCH - 2) {
                stage(c + 2);                             // 2 chunks in flight
                asm volatile("s_waitcnt vmcnt(32)" ::: "memory"); // c+1 landed
            } else {
                asm volatile("s_waitcnt vmcnt(0)" ::: "memory");  // tail drain
            }
            __builtin_amdgcn_sched_barrier(0);
            __builtin_amdgcn_s_barrier();
        }
    } else {
        // ---------------- consumer wave: LDS reads only, zero VMEM in loop -
        const int* __restrict__ lb = yt + b * L_LEN;
        const int l0 = lb[2 * lane];                    // state 4l+1
        const int l1 = lb[2 * lane + 1];                // state 4l+3
        const int lp = lane ? lb[2 * lane - 1] : 0;
        const float sk1 = (lane > 0 && l0 != lp && l0 != BLANK) ? 1.0f : 0.0f;
        const float sk3 = (l1 != l0 && l1 != BLANK) ? 1.0f : 0.0f;

        // "t=-1" init: a0=1 on lane 0 makes step t=0 produce exactly alpha0.
        float a0 = (lane == 0) ? 1.0f : 0.0f;
        float a1 = 0.0f, a2 = 0.0f, a3 = 0.0f, a4 = 0.0f;
        int   E  = 0;                                   // per-lane exponent
        float sSeed = (lane == 0) ? 0.0f : 1.0f;        // 2^(E_prev-E), 0 masks lane 0

        __builtin_amdgcn_s_barrier();                   // matches producer prologue

        float4 ring[8];
#pragma unroll 1
        for (int c = 0; c < NCH; ++c) {
            __builtin_amdgcn_sched_barrier(0);          // no reads above barrier
            const float4* sb = &sbuf[c & (NBUF - 1)][0][lane];
#pragma unroll
            for (int i = 0; i < 8; ++i) ring[i] = sb[i * 64];

#pragma unroll
            for (int tq = 0; tq < TC / 8; ++tq) {
#pragma unroll
                for (int i = 0; i < 8; ++i) {
                    const float P1 = ring[i].x;
                    const float P3 = ring[i].y;
                    const float Pb = ring[i].z;
                    if (tq < TC / 8 - 1)
                        ring[i] = sb[(tq * 8 + i + 8) * 64];

                    const float pa3 = wshr1_f(a3) * sSeed;  // alpha[4l-1], rescaled
                    const float n0 = Pb * (a0 + pa3);
                    const float n1 = P1 * (a1 + a0 + sk1 * pa3);
                    const float n2 = Pb * (a2 + a1);
                    const float n3 = P3 * (a3 + a2 + sk3 * a1);
                    const float n4 = Pb * (a4 + a3);
                    a0 = n0; a1 = n1; a2 = n2; a3 = n3; a4 = n4;

                    if ((i & 3) == 3) {
                        // per-lane rescale every 4 steps (decay >= (1e-7)^4)
                        const float m = fmaxf(fmaxf(fmaxf(a0, a1), fmaxf(a2, a3)), a4);
                        const bool has = m > 0.0f;
                        int eb = (int)((__float_as_uint(m) >> 23) & 0xFFu);
                        eb = eb < 1 ? 1 : eb;           // denormal m -> scale up
                        if (has) {
                            const float scl = __uint_as_float((unsigned)(254 - eb) << 23);
                            a0 *= scl; a1 *= scl; a2 *= scl; a3 *= scl; a4 *= scl;
                            E += eb - 127;
                        }
                        int pE = wshr1_i(E);
                        if (!has && lane > 0) E = pE;   // empty lane adopts neighbor's E
                        pE = wshr1_i(E);
                        const int d = pE - E;
                        sSeed = (lane == 0 || d < -126)
                              ? 0.0f
                              : __uint_as_float((unsigned)(127 + (d > 126 ? 126 : d)) << 23);
                    }
                }
            }
            __builtin_amdgcn_sched_barrier(0);          // no reads below barrier
            __builtin_amdgcn_s_barrier();
        }

        if (lane == 63)                                 // states 255 (a3) + 256 (a4)
            out[b] = -((log2f(a3 + a4) + (float)E) * LN2F);
    }
}

// Fallback (no workspace): direct 3-gather scan on yh.
__global__ __launch_bounds__(64, 1)
void ctc_scan_direct(const int* __restrict__ yt, const float* __restrict__ src,
                     float* __restrict__ out)
{
    const int b    = blockIdx.x;
    const int lane = threadIdx.x;
    const int* __restrict__ lb = yt + b * L_LEN;

    const int l0 = lb[2 * lane];
    const int l1 = lb[2 * lane + 1];
    const int lp = lane ? lb[2 * lane - 1] : 0;
    const float sk1 = (lane > 0 && l0 != lp && l0 != BLANK) ? 1.0f : 0.0f;
    const float sk3 = (l1 != l0 && l1 != BLANK) ? 1.0f : 0.0f;

    const float* __restrict__ base = src + (size_t)b * T_LEN * C_DIM;

    float a0 = (lane == 0) ? 1.0f : 0.0f;
    float a1 = 0.0f, a2 = 0.0f, a3 = 0.0f, a4 = 0.0f;
    int   E  = 0;
    float sSeed = (lane == 0) ? 0.0f : 1.0f;

    constexpr int DP = 16;
    float pb[DP], p1[DP], p3[DP];
    auto LOADT = [&](int slot, int t) {
        const float* row = base + (size_t)t * C_DIM;
        pb[slot] = row[BLANK]; p1[slot] = row[l0]; p3[slot] = row[l1];
    };
#pragma unroll
    for (int i = 0; i < DP; ++i) LOADT(i, i);

#pragma unroll 1
    for (int blk = 0; blk < T_LEN / DP; ++blk) {
#pragma unroll
        for (int q = 0; q < DP / 4; ++q) {
#pragma unroll
            for (int i = 0; i < 4; ++i) {
                const int slot = q * 4 + i;
                const float Pb = pb[slot] + EPSF;
                const float P1 = p1[slot] + EPSF;
                const float P3 = p3[slot] + EPSF;
                int tn = blk * DP + slot + DP;
                tn = tn < T_LEN ? tn : T_LEN - 1;
                LOADT(slot, tn);
                const float pa3 = wshr1_f(a3) * sSeed;
                const float n0 = Pb * (a0 + pa3);
                const float n1 = P1 * (a1 + a0 + sk1 * pa3);
                const float n2 = Pb * (a2 + a1);
                const float n3 = P3 * (a3 + a2 + sk3 * a1);
                const float n4 = Pb * (a4 + a3);
                a0 = n0; a1 = n1; a2 = n2; a3 = n3; a4 = n4;
            }
            const float m = fmaxf(fmaxf(fmaxf(a0, a1), fmaxf(a2, a3)), a4);
            const bool has = m > 0.0f;
            int eb = (int)((__float_as_uint(m) >> 23) & 0xFFu);
            eb = eb < 1 ? 1 : eb;
            if (has) {
                const float scl = __uint_as_float((unsigned)(254 - eb) << 23);
                a0 *= scl; a1 *= scl; a2 *= scl; a3 *= scl; a4 *= scl;
                E += eb - 127;
            }
            int pE = wshr1_i(E);
            if (!has && lane > 0) E = pE;
            pE = wshr1_i(E);
            const int d = pE - E;
            sSeed = (lane == 0 || d < -126)
                  ? 0.0f
                  : __uint_as_float((unsigned)(127 + (d > 126 ? 126 : d)) << 23);
        }
    }

    if (lane == 63)
        out[b] = -((log2f(a3 + a4) + (float)E) * LN2F);
}

extern "C" void kernel_launch(void* const* d_in, const int* in_sizes, int n_in,
                              void* d_out, int out_size, void* d_ws, size_t ws_size,
                              hipStream_t stream)
{
    const int*   yt  = (const int*)d_in[0];
    const float* yh  = (const float*)d_in[1];
    float*       out = (float*)d_out;

    const size_t need = (size_t)B_DIM * T_LEN * 64 * sizeof(float4);
    if (d_ws != nullptr && ws_size >= need) {
        float4* cmp = (float4*)d_ws;
        constexpr int NTOT = B_DIM * T_LEN * 64;
        ctc_gather4<<<dim3((NTOT + 255) / 256), dim3(256), 0, stream>>>(yt, yh, cmp);
        ctc_scan_pc<<<dim3(B_DIM), dim3(128), 0, stream>>>(yt, cmp, out);
    } else {
        ctc_scan_direct<<<dim3(B_DIM), dim3(64), 0, stream>>>(yt, yh, out);
    }
}

// Round 13
// 71.254 us; speedup vs baseline: 1.8537x; 1.1981x over previous
//
#include <hip/hip_runtime.h>

// CTC batch cost (Keras: blank=C-1, full lengths). SINGLE fused kernel.
// One block per batch row: wave 1 = producer, wave 0 = consumer (R12 skeleton,
// proven correct). R13 change: producer gathers DIRECTLY from y_hat using
// global_load_lds's per-lane GLOBAL source (m173; R12 already used lane-
// dependent sources): one size-4 load = p[label] for 64 odd-state columns,
// one for the other 64, blanks for all T staged in a 16-load prologue
// (lane<->timestep, col 511). Eliminates the gather kernel and the 67MB
// intermediate write + 67MB re-read (268MB -> 134MB total traffic).
// Counted vmcnt(32) (TC=16 -> 32 loads/chunk, <=63 encodable), 2 chunks in
// flight, raw s_barrier (no auto-drain), consumer VMEM-free in its loop.
// DPP wave_shr:1 cross-lane shift; per-lane pow2 rescale every 4 steps
// (unbounded dynamic range; absmax 0.0 since R2 whenever mechanics right).

constexpr int   B_DIM = 64;
constexpr int   T_LEN = 1024;
constexpr int   C_DIM = 512;
constexpr int   L_LEN = 128;
constexpr int   BLANK = C_DIM - 1;
constexpr int   TC    = 16;            // timesteps per chunk
constexpr int   NCH   = T_LEN / TC;    // 64 chunks
constexpr int   NBUF  = 4;             // chunk buffers in LDS
constexpr float EPSF  = 1e-7f;
constexpr float LN2F  = 0.69314718055994530942f;

// lane l <- lane l-1, lane 0 <- 0 (DPP wave_shr:1, bound_ctrl=0-fill). VALU-only.
__device__ __forceinline__ float wshr1_f(float x) {
    return __int_as_float(__builtin_amdgcn_update_dpp(
        0, __float_as_int(x), 0x138, 0xf, 0xf, true));
}
__device__ __forceinline__ int wshr1_i(int x) {
    return __builtin_amdgcn_update_dpp(0, x, 0x138, 0xf, 0xf, true);
}

__global__ __launch_bounds__(128, 1)
void ctc_fused(const int* __restrict__ yt, const float* __restrict__ yh,
               float* __restrict__ out)
{
    __shared__ float sbuf[NBUF][TC][2][64];   // [buf][i][0]=p(l0) [1]=p(l1), 32KB
    __shared__ float sblk[T_LEN / 64][64];    // blank[t>>6][t&63], 4KB

    const int b    = blockIdx.x;
    const int tid  = threadIdx.x;
    const int lane = tid & 63;
    const int wid  = tid >> 6;                // 0 = consumer, 1 = producer

    const int* __restrict__ lb = yt + b * L_LEN;
    const float* __restrict__ yhb = yh + (size_t)b * T_LEN * C_DIM;

    if (wid == 1) {
        // ---------------- producer: gather-staging directly from y_hat -----
        const int c1 = lb[2 * lane];                  // column for state 4l+1
        const int c3 = lb[2 * lane + 1];              // column for state 4l+3
        const float* g1 = yhb + c1;                   // per-lane source ptrs
        const float* g3 = yhb + c3;
        const float* gB = yhb + (size_t)lane * C_DIM + BLANK;  // lane<->timestep

        auto stage = [&](int ch) {                    // 2*TC size-4 loads
            float* d = &sbuf[ch & (NBUF - 1)][0][0][0];
#pragma unroll
            for (int i = 0; i < TC; ++i) {
                const int t = ch * TC + i;
                __builtin_amdgcn_global_load_lds(
                    (const __attribute__((address_space(1))) void*)(g1 + (size_t)t * C_DIM),
                    (__attribute__((address_space(3))) void*)(d + i * 128), 4, 0, 0);
                __builtin_amdgcn_global_load_lds(
                    (const __attribute__((address_space(1))) void*)(g3 + (size_t)t * C_DIM),
                    (__attribute__((address_space(3))) void*)(d + i * 128 + 64), 4, 0, 0);
            }
        };

        asm volatile("s_waitcnt vmcnt(0)" ::: "memory");   // clean count baseline
        // blanks for ALL timesteps: 16 loads, lane l covers t = j*64+l
#pragma unroll
        for (int j = 0; j < T_LEN / 64; ++j) {
            __builtin_amdgcn_global_load_lds(
                (const __attribute__((address_space(1))) void*)(gB + (size_t)j * 64 * C_DIM),
                (__attribute__((address_space(3))) void*)&sblk[j][0], 4, 0, 0);
        }
        stage(0);
        stage(1);
        // blanks(16)+chunk0(32) landed; chunk1's 32 still outstanding
        asm volatile("s_waitcnt vmcnt(32)" ::: "memory");
        __builtin_amdgcn_sched_barrier(0);
        __builtin_amdgcn_s_barrier();                      // raw: no auto-drain
#pragma unroll 1
        for (int c = 0; c < NCH; ++c) {
            if (c < NCH - 2) {
                stage(c + 2);                              // 2 chunks in flight
                asm volatile("s_waitcnt vmcnt(32)" ::: "memory");  // c+1 landed
            } else {
                asm volatile("s_waitcnt vmcnt(0)" ::: "memory");   // tail drain
            }
            __builtin_amdgcn_sched_barrier(0);
            __builtin_amdgcn_s_barrier();
        }
    } else {
        // ---------------- consumer: LDS only in loop, zero VMEM ------------
        const int l0 = lb[2 * lane];
        const int l1 = lb[2 * lane + 1];
        const int lp = lane ? lb[2 * lane - 1] : 0;
        const float sk1 = (lane > 0 && l0 != lp && l0 != BLANK) ? 1.0f : 0.0f;
        const float sk3 = (l1 != l0 && l1 != BLANK) ? 1.0f : 0.0f;

        // "t=-1" init: a0=1 on lane 0 makes step t=0 produce exactly alpha0.
        float a0 = (lane == 0) ? 1.0f : 0.0f;
        float a1 = 0.0f, a2 = 0.0f, a3 = 0.0f, a4 = 0.0f;
        int   E  = 0;                                   // per-lane exponent
        float sSeed = (lane == 0) ? 0.0f : 1.0f;        // 2^(E_prev-E), 0 on lane 0

        __builtin_amdgcn_s_barrier();                   // matches producer prologue

        float r1[8], r3[8], rb[8];
#pragma unroll 1
        for (int c = 0; c < NCH; ++c) {
            __builtin_amdgcn_sched_barrier(0);          // no LDS reads above barrier
            const float* sb = &sbuf[c & (NBUF - 1)][0][0][lane];
            const int t0 = c * TC;
#pragma unroll
            for (int i = 0; i < 8; ++i) {
                r1[i] = sb[i * 128];
                r3[i] = sb[i * 128 + 64];
                rb[i] = sblk[(t0 + i) >> 6][(t0 + i) & 63];
            }
#pragma unroll
            for (int tq = 0; tq < TC / 8; ++tq) {
#pragma unroll
                for (int i = 0; i < 8; ++i) {
                    const float P1 = r1[i] + EPSF;
                    const float P3 = r3[i] + EPSF;
                    const float Pb = rb[i] + EPSF;
                    if (tq < TC / 8 - 1) {
                        r1[i] = sb[(i + 8) * 128];
                        r3[i] = sb[(i + 8) * 128 + 64];
                        rb[i] = sblk[(t0 + i + 8) >> 6][(t0 + i + 8) & 63];
                    }

                    const float pa3 = wshr1_f(a3) * sSeed;  // alpha[4l-1]
                    const float n0 = Pb * (a0 + pa3);
                    const float n1 = P1 * (a1 + a0 + sk1 * pa3);
                    const float n2 = Pb * (a2 + a1);
                    const float n3 = P3 * (a3 + a2 + sk3 * a1);
                    const float n4 = Pb * (a4 + a3);
                    a0 = n0; a1 = n1; a2 = n2; a3 = n3; a4 = n4;

                    if ((i & 3) == 3) {
                        // per-lane rescale every 4 steps (decay >= (1e-7)^4)
                        const float m = fmaxf(fmaxf(fmaxf(a0, a1), fmaxf(a2, a3)), a4);
                        const bool has = m > 0.0f;
                        int eb = (int)((__float_as_uint(m) >> 23) & 0xFFu);
                        eb = eb < 1 ? 1 : eb;           // denormal m -> scale up
                        if (has) {
                            const float scl = __uint_as_float((unsigned)(254 - eb) << 23);
                            a0 *= scl; a1 *= scl; a2 *= scl; a3 *= scl; a4 *= scl;
                            E += eb - 127;
                        }
                        int pE = wshr1_i(E);
                        if (!has && lane > 0) E = pE;   // empty lane adopts E
                        pE = wshr1_i(E);
                        const int d = pE - E;
                        sSeed = (lane == 0 || d < -126)
                              ? 0.0f
                              : __uint_as_float((unsigned)(127 + (d > 126 ? 126 : d)) << 23);
                    }
                }
            }
            __builtin_amdgcn_sched_barrier(0);          // no LDS reads below barrier
            __builtin_amdgcn_s_barrier();
        }

        if (lane == 63)                                 // states 255 (a3) + 256 (a4)
            out[b] = -((log2f(a3 + a4) + (float)E) * LN2F);
    }
}

extern "C" void kernel_launch(void* const* d_in, const int* in_sizes, int n_in,
                              void* d_out, int out_size, void* d_ws, size_t ws_size,
                              hipStream_t stream)
{
    const int*   yt  = (const int*)d_in[0];
    const float* yh  = (const float*)d_in[1];
    float*       out = (float*)d_out;
    ctc_fused<<<dim3(B_DIM), dim3(128), 0, stream>>>(yt, yh, out);
}